// Round 14
// baseline (176449.634 us; speedup 1.0000x reference)
//
#include <hip/hip_runtime.h>
#include <math.h>

#define BATCH 128
#define TSTEPS 1024
#define INSZ 256
#define HSZ 256
#define MEMN 128

#define NWG_A 16
#define NWG_B 16
#define NWG_C 8
#define NWG 40
#define NTHR 1024
#define FSP 16   // flag spread (ints) -> 64B apart

#define GATE_C 0.40131233988754794f
#define OMG_C  (1.0f - GATE_C)
#define GAMMA_C 0.3f

// ---- per-step state, unique slot per t (WT-produced, cached-read consumed) ----
__device__ float g_zx [(size_t)TSTEPS * 4 * HSZ * BATCH];  // zx(t)[g][j][b]
__device__ float g_hB [(size_t)TSTEPS * BATCH * HSZ];      // h(t)[b][j]
__device__ float g_hT [(size_t)TSTEPS * HSZ * BATCH];      // hT(t)[j][b]
__device__ float g_M  [(size_t)TSTEPS * MEMN * HSZ];       // M(t), slots 1..1023
__device__ float g_Mn [(size_t)TSTEPS * MEMN];
__device__ float g_wwT[(size_t)TSTEPS * MEMN * BATCH];     // wwT(t)[m][b], slots 1..1023
__device__ int g_fA[TSTEPS * NWG_A * FSP];
__device__ int g_fB[TSTEPS * NWG_B * FSP];
__device__ int g_fC[TSTEPS * NWG_C * FSP];

__global__ void reset_ctrl_kernel() {
    const int gt = blockIdx.x * 256 + threadIdx.x, gn = gridDim.x * 256;
    for (int i = gt; i < TSTEPS * NWG_A * FSP; i += gn)
        __hip_atomic_store(&g_fA[i], 0, __ATOMIC_RELAXED, __HIP_MEMORY_SCOPE_AGENT);
    for (int i = gt; i < TSTEPS * NWG_B * FSP; i += gn)
        __hip_atomic_store(&g_fB[i], 0, __ATOMIC_RELAXED, __HIP_MEMORY_SCOPE_AGENT);
    for (int i = gt; i < TSTEPS * NWG_C * FSP; i += gn)
        __hip_atomic_store(&g_fC[i], 0, __ATOMIC_RELAXED, __HIP_MEMORY_SCOPE_AGENT);
}

__device__ __forceinline__ float sigf(float x) { return 1.0f / (1.0f + expf(-x)); }
__device__ __forceinline__ void st_wt(float* p, float v) {
    __hip_atomic_store(p, v, __ATOMIC_RELAXED, __HIP_MEMORY_SCOPE_AGENT);
}
__device__ __forceinline__ void st_wt2(float* p, float lo, float hi) {
    unsigned long long pk = (unsigned long long)__float_as_uint(lo) |
                            ((unsigned long long)__float_as_uint(hi) << 32);
    __hip_atomic_store((unsigned long long*)p, pk, __ATOMIC_RELAXED, __HIP_MEMORY_SCOPE_AGENT);
}
__device__ __forceinline__ void st_flag(int* p, int v) {
    (void)__hip_atomic_exchange(p, v, __ATOMIC_RELAXED, __HIP_MEMORY_SCOPE_AGENT);
}
__device__ __forceinline__ void wait_vm0() { asm volatile("s_waitcnt vmcnt(0)" ::: "memory"); }

// wave scan over spread flags
__device__ __forceinline__ void wait_flags16(int* f, int n, int want, int lane) {
    int it = 0;
    for (;;) {
        bool ok = true;
        for (int i = lane; i < n; i += 64)
            ok &= (__hip_atomic_load(&f[i * FSP], __ATOMIC_RELAXED, __HIP_MEMORY_SCOPE_AGENT) == want);
        if (__all(ok)) break;
        __builtin_amdgcn_s_sleep(8);
        if (++it > (1 << 20)) break;  // hang valve
    }
}

// ================= zx precompute (R9/R10-verified, unchanged) =================
__global__ void __launch_bounds__(256, 2)
pre_kernel(const float* __restrict__ X, const float* __restrict__ Wih,
           const float* __restrict__ bih, const float* __restrict__ bhh) {
    __shared__ float4 p_x[4096];
    const int w = blockIdx.x, tid = threadIdx.x;
    const int t = w >> 1, half = w & 1;
#pragma unroll
    for (int rep = 0; rep < 16; ++rep) {
        const int idx = rep * 256 + tid;
        const int bl = idx >> 6, c = idx & 63;
        p_x[bl * 64 + (c ^ bl)] =
            *(const float4*)&X[((size_t)(half * 64 + bl) * TSTEPS + t) * INSZ + c * 4];
    }
    __syncthreads();
    const int bl = tid & 63, hf2 = tid >> 6;
    const int b = half * 64 + bl;
    const float4* wih4 = (const float4*)Wih;
    for (int jb4 = 0; jb4 < 16; ++jb4) {
        float a16[16];
#pragma unroll
        for (int i = 0; i < 16; ++i) a16[i] = 0.f;
#pragma unroll 4
        for (int c = 0; c < 64; ++c) {
            const float4 xv = p_x[bl * 64 + (c ^ bl)];
#pragma unroll
            for (int g = 0; g < 4; ++g)
#pragma unroll
                for (int j4 = 0; j4 < 4; ++j4) {
                    const int row = g * HSZ + hf2 * 64 + jb4 * 4 + j4;
                    const float4 wv4 = wih4[(size_t)row * 64 + c];
                    a16[g * 4 + j4] += wv4.x * xv.x + wv4.y * xv.y + wv4.z * xv.z + wv4.w * xv.w;
                }
        }
#pragma unroll
        for (int g = 0; g < 4; ++g)
#pragma unroll
            for (int j4 = 0; j4 < 4; ++j4) {
                const int j = hf2 * 64 + jb4 * 4 + j4;
                const int row = g * HSZ + j;
                g_zx[(((size_t)t * 4 + g) * HSZ + j) * BATCH + b] =
                    a16[g * 4 + j4] + bih[row] + bhh[row];
            }
    }
}

// ================= persistent A/B/C, 1024-thread WGs =================
__global__ void __launch_bounds__(NTHR, 1)
mann_persist(const float* __restrict__ Whh, float* __restrict__ out) {
    __shared__ __align__(16) float s_raw[36864];  // 144 KB, class-carved
    __shared__ float s_rw[64];                    // per-wave reduction slots (x4)
    __shared__ unsigned long long s_ru[16];

    const int w = blockIdx.x, tid = threadIdx.x;
    const int lane = tid & 63, wv = tid >> 6;

    // ---- reductions over 128-thread groups (wave pairs) ----
    auto grpsum = [&](float v) -> float {
#pragma unroll
        for (int o = 32; o; o >>= 1) v += __shfl_xor(v, o, 64);
        if (lane == 0) s_rw[wv] = v;
        __syncthreads();
        float r = s_rw[(tid >> 7) * 2] + s_rw[(tid >> 7) * 2 + 1];
        __syncthreads();
        return r;
    };
    auto grpmax = [&](float v) -> float {
#pragma unroll
        for (int o = 32; o; o >>= 1) v = fmaxf(v, __shfl_xor(v, o, 64));
        if (lane == 0) s_rw[wv] = v;
        __syncthreads();
        float r = fmaxf(s_rw[(tid >> 7) * 2], s_rw[(tid >> 7) * 2 + 1]);
        __syncthreads();
        return r;
    };
    auto grpminu = [&](unsigned long long v) -> unsigned long long {
#pragma unroll
        for (int o = 32; o; o >>= 1) {
            unsigned long long o2 = __shfl_xor(v, o, 64);
            v = (o2 < v) ? o2 : v;
        }
        if (lane == 0) s_ru[wv] = v;
        __syncthreads();
        unsigned long long a = s_ru[(tid >> 7) * 2], b2 = s_ru[(tid >> 7) * 2 + 1];
        unsigned long long r = (a < b2) ? a : b2;
        __syncthreads();
        return r;
    };
    // 4-value sum over 256-thread group (4 waves), tree (s0+s1)+(s2+s3)
    auto red4g = [&](float v0, float v1, float v2, float v3, float (&r)[4]) {
#pragma unroll
        for (int o = 32; o; o >>= 1) {
            v0 += __shfl_xor(v0, o, 64);
            v1 += __shfl_xor(v1, o, 64);
            v2 += __shfl_xor(v2, o, 64);
            v3 += __shfl_xor(v3, o, 64);
        }
        if (lane == 0) {
            s_rw[wv * 4 + 0] = v0; s_rw[wv * 4 + 1] = v1;
            s_rw[wv * 4 + 2] = v2; s_rw[wv * 4 + 3] = v3;
        }
        __syncthreads();
        const int g4 = (tid >> 8) * 4;
#pragma unroll
        for (int k = 0; k < 4; ++k)
            r[k] = (s_rw[(g4 + 0) * 4 + k] + s_rw[(g4 + 1) * 4 + k]) +
                   (s_rw[(g4 + 2) * 4 + k] + s_rw[(g4 + 3) * 4 + k]);
        __syncthreads();
    };

    if (w < NWG_A) {
        // ====== A: h(t) = LSTM(zx(t), h(t-1)); 16 WGs x 1024 thr ======
        const int bb = w >> 3, j3 = w & 7;       // batch half, 32-j block
        const int jA = j3 * 32 + (wv >> 2) * 8 + (wv & 3) * 2;  // this wave's 2 j rows
        const int ljA = (wv >> 2) * 8 + (wv & 3) * 2;           // local row in s_tr
        const int bglob = bb * 64 + lane;
        float4* s_h4 = (float4*)s_raw;            // [64 b][64 c4] swizzled, 64 KB
        float* s_tr = s_raw + 16384;              // [32 j][64 b]
        float creg0 = 0.f, creg1 = 0.f;
        float zxr[8];
#pragma unroll
        for (int g = 0; g < 4; ++g)
#pragma unroll
            for (int jj = 0; jj < 2; ++jj)
                zxr[g * 2 + jj] = g_zx[((size_t)(0 * 4 + g) * HSZ + jA + jj) * BATCH + bglob];

        for (int t = 0; t < TSTEPS; ++t) {
            float acc[8] = {0.f, 0.f, 0.f, 0.f, 0.f, 0.f, 0.f, 0.f};
            if (t > 0) {
#pragma unroll 8
                for (int c = 0; c < 64; ++c) {
                    const float4 xv = s_h4[lane * 64 + (c ^ (lane & 7))];
#pragma unroll
                    for (int g = 0; g < 4; ++g)
#pragma unroll
                        for (int jj = 0; jj < 2; ++jj) {
                            const float4 w4 =
                                *(const float4*)&Whh[(size_t)(g * HSZ + jA + jj) * HSZ + c * 4];
                            acc[g * 2 + jj] += w4.x * xv.x + w4.y * xv.y + w4.z * xv.z + w4.w * xv.w;
                        }
                }
            }
#pragma unroll
            for (int jj = 0; jj < 2; ++jj) {
                const float z0 = zxr[0 * 2 + jj] + acc[0 * 2 + jj];
                const float z1 = zxr[1 * 2 + jj] + acc[1 * 2 + jj];
                const float z2 = zxr[2 * 2 + jj] + acc[2 * 2 + jj];
                const float z3 = zxr[3 * 2 + jj] + acc[3 * 2 + jj];
                float cr = jj ? creg1 : creg0;
                const float cn = sigf(z1) * cr + sigf(z0) * tanhf(z2);
                const float hn = sigf(z3) * tanhf(cn);
                if (jj) creg1 = cn; else creg0 = cn;
                s_tr[(ljA + jj) * 64 + lane] = hn;
            }
            __syncthreads();  // s_tr complete; s_h4 reads done
            if (wv == 0) {
                // j-major publish: 32 coalesced rows
#pragma unroll 8
                for (int r = 0; r < 32; ++r)
                    st_wt(&g_hT[((size_t)t * HSZ + j3 * 32 + r) * BATCH + bb * 64 + lane],
                          s_tr[r * 64 + lane]);
                // b-major publish: 16 insts of (4 b x 16 j-pairs)
#pragma unroll 4
                for (int i = 0; i < 16; ++i) {
                    const int b = i * 4 + (lane >> 4), jp = (lane & 15) * 2;
                    st_wt2(&g_hB[((size_t)t * BATCH + bb * 64 + b) * HSZ + j3 * 32 + jp],
                           s_tr[jp * 64 + b], s_tr[(jp + 1) * 64 + b]);
                }
                wait_vm0();
                if (lane == 0) st_flag(&g_fA[((size_t)t * NWG_A + w) * FSP], t + 1);
            } else if (wv == 15 && t + 1 < TSTEPS) {
                // concurrent with wave0's drain: observe half's producers (incl self)
                wait_flags16(g_fA + ((size_t)t * NWG_A + bb * 8) * FSP, 8, t + 1, lane);
            }
            __syncthreads();  // flag set; poll done
            if (t + 1 < TSTEPS) {
                // stage h(t) for next iter
#pragma unroll
                for (int rep = 0; rep < 4; ++rep) {
                    const int id = rep * 1024 + tid, b = id >> 6, c = id & 63;
                    s_h4[b * 64 + (c ^ (b & 7))] =
                        *(const float4*)&g_hB[((size_t)t * BATCH + bb * 64 + b) * HSZ + c * 4];
                }
#pragma unroll
                for (int g = 0; g < 4; ++g)
#pragma unroll
                    for (int jj = 0; jj < 2; ++jj)
                        zxr[g * 2 + jj] =
                            g_zx[((size_t)((t + 1) * 4 + g) * HSZ + jA + jj) * BATCH + bglob];
            }
            __syncthreads();
        }
    } else if (w < NWG_A + NWG_B) {
        // ====== B: read head + output + w_u/w_w; 16 WGs x 8 batches ======
        const int nb = w - NWG_A;
        const int half = nb >> 3;
        const int grp = tid >> 7, lm = tid & 127;   // 8 batch groups of 128 threads
        const int bB = nb * 8 + grp;
        float* s_M = s_raw;              // [128][256] 128 KB
        float* s_h2 = s_raw + 32768;     // [8][256]
        float* s_wr2 = s_raw + 34816;    // [8][128]
        float* s_wwB = s_raw + 35840;    // [8][128]
        float wwreg = (lm == 0) ? OMG_C : 0.f;
        float wureg = 0.f;

        if (wv == 0) wait_flags16(g_fA + (size_t)(half * 8) * FSP, 8, 1, lane);
        __syncthreads();

        for (int t = 0; t < TSTEPS; ++t) {
            if (t > 0) {  // M(t) stage (C-flag(t-1) confirmed by end-poll of prev iter)
                float4 mt[8];
                const float4* msrc = (const float4*)&g_M[(size_t)t * MEMN * HSZ];
#pragma unroll
                for (int i = 0; i < 8; ++i) mt[i] = msrc[i * 1024 + tid];
                float4* md = (float4*)s_M;
#pragma unroll
                for (int i = 0; i < 8; ++i) md[i * 1024 + tid] = mt[i];
            }
            s_h2[grp * 256 + lm] = g_hB[((size_t)t * BATCH + bB) * HSZ + lm];
            s_h2[grp * 256 + 128 + lm] = g_hB[((size_t)t * BATCH + bB) * HSZ + 128 + lm];
            __syncthreads();
            const float hv0 = s_h2[grp * 256 + lm], hv1 = s_h2[grp * 256 + lm + 128];
            const float hnorm = sqrtf(grpsum(hv0 * hv0 + hv1 * hv1));
            float sc = 0.f;
            if (t > 0) {
                const float4* mrow = (const float4*)&s_M[(size_t)lm * HSZ];
                const float4* h4 = (const float4*)&s_h2[grp * 256];
                const int sw = lm & 7;
                float a = 0.f;
#pragma unroll 8
                for (int c = 0; c < 64; ++c) {
                    const int ci = c ^ sw;
                    const float4 m4 = mrow[ci], x4 = h4[ci];
                    a += m4.x * x4.x + m4.y * x4.y + m4.z * x4.z + m4.w * x4.w;
                }
                const float mn = g_Mn[(size_t)t * MEMN + lm];
                sc = a / (hnorm * mn + 1e-8f);
            }
            const float mx = grpmax(sc);
            const float ev = expf(sc - mx);
            const float es = grpsum(ev);
            const float wr = ev / es;
            s_wr2[grp * 128 + lm] = wr;
            __syncthreads();
            // chain: wu/ww update
            const float un = GAMMA_C * wureg + wr + wwreg;
            const float un2 = grpsum(un * un);
            const float us = 1.0f / fmaxf(sqrtf(un2), 1e-12f);
            const float wun = un * us;
            wureg = wun;
            unsigned long long key =
                (((unsigned long long)__float_as_uint(wun)) << 32) | (unsigned)lm;
            const unsigned long long mk = grpminu(key);
            const int amin = (int)(mk & 0xffffffffu);
            const float wwn = GATE_C * wr + ((lm == amin) ? OMG_C : 0.f);
            wwreg = wwn;
            s_wwB[grp * 128 + lm] = wwn;
            // off-chain: read vector + out (issued, drains lazily)
            float rd0 = 0.f, rd1 = 0.f;
            if (t > 0) {
#pragma unroll 8
                for (int m = 0; m < 128; ++m) {
                    const float wrm = s_wr2[grp * 128 + m];
                    rd0 += wrm * s_M[m * HSZ + lm];
                    rd1 += wrm * s_M[m * HSZ + 128 + lm];
                }
            }
            float* o = out + ((size_t)bB * TSTEPS + t) * 512;
            o[lm] = hv0;
            o[128 + lm] = hv1;
            o[256 + lm] = rd0;
            o[384 + lm] = rd1;
            __syncthreads();  // s_wwB ready; compute done
            if (wv == 0) {
                if (t + 1 < TSTEPS) {
#pragma unroll 4
                    for (int i = 0; i < 16; ++i) {
                        const int m = i * 8 + (lane >> 3), bl = lane & 7;
                        st_wt(&g_wwT[((size_t)(t + 1) * MEMN + m) * BATCH + nb * 8 + bl],
                              s_wwB[bl * 128 + m]);
                    }
                }
                wait_vm0();
                if (lane == 0) st_flag(&g_fB[((size_t)t * NWG_B + nb) * FSP], t + 1);
            } else if (wv == 14 && t + 1 < TSTEPS) {
                wait_flags16(g_fC + (size_t)t * NWG_C * FSP, NWG_C, t + 1, lane);
            } else if (wv == 15 && t + 1 < TSTEPS) {
                wait_flags16(g_fA + ((size_t)(t + 1) * NWG_A + half * 8) * FSP, 8, t + 2, lane);
            }
            __syncthreads();
        }
    } else {
        // ====== C: M(t+1) = l2norm(M(t) + ww(t)^T h(t)); 8 WGs x 16 m-rows ======
        const int nc = w - NWG_A - NWG_B;
        const int m0 = nc * 16;
        const int jj = tid & 255, mq = tid >> 8;   // 4 m-quads of 256 j-threads
        float* s_wwc = s_raw;            // [16 m][128 b]
        float* s_pub = s_raw + 2048;     // [16 m][256 j]
        float* s_Mn = s_raw + 6144;      // [16]
        float mreg[4] = {0.f, 0.f, 0.f, 0.f};

        if (wv == 0) wait_flags16(g_fA, NWG_A, 1, lane);
        __syncthreads();

        for (int t = 0; t < TSTEPS - 1; ++t) {
            // stage ww(t) (B-flag(t-1) confirmed by end-poll of prev iter)
#pragma unroll
            for (int rep = 0; rep < 2; ++rep) {
                const int e = rep * 1024 + tid, mi = e >> 7, b = e & 127;
                float v;
                if (t > 0) v = g_wwT[((size_t)t * MEMN + m0 + mi) * BATCH + b];
                else v = (m0 + mi == 0) ? OMG_C : 0.f;
                s_wwc[mi * 128 + b] = v;
            }
            __syncthreads();
            float macc[4];
#pragma unroll
            for (int mi = 0; mi < 4; ++mi) macc[mi] = mreg[mi];
            const float4* ht4 = (const float4*)&g_hT[((size_t)t * HSZ + jj) * BATCH];
#pragma unroll
            for (int cb = 0; cb < 4; ++cb) {
                float4 hb8[8];
#pragma unroll
                for (int q = 0; q < 8; ++q) hb8[q] = ht4[cb * 8 + q];
#pragma unroll
                for (int q = 0; q < 8; ++q) {
                    const float4 hv4 = hb8[q];
#pragma unroll
                    for (int mi = 0; mi < 4; ++mi) {
                        const float* wc = &s_wwc[(mq * 4 + mi) * 128 + (cb * 8 + q) * 4];
                        macc[mi] += wc[0] * hv4.x + wc[1] * hv4.y + wc[2] * hv4.z + wc[3] * hv4.w;
                    }
                }
            }
            float nr[4];
            red4g(macc[0] * macc[0], macc[1] * macc[1],
                  macc[2] * macc[2], macc[3] * macc[3], nr);
#pragma unroll
            for (int mi = 0; mi < 4; ++mi) {
                const float nrm = sqrtf(nr[mi]);
                const float scale = 1.0f / fmaxf(nrm, 1e-12f);
                const float vo = macc[mi] * scale;
                mreg[mi] = vo;
                s_pub[(mq * 4 + mi) * 256 + jj] = vo;
                if (jj == 0) s_Mn[mq * 4 + mi] = nrm * scale;
            }
            __syncthreads();  // s_pub + s_Mn ready
            if (wv == 0) {
#pragma unroll 4
                for (int r = 0; r < 16; ++r)
#pragma unroll
                    for (int hh = 0; hh < 2; ++hh) {
                        const int jp = hh * 128 + lane * 2;
                        st_wt2(&g_M[((size_t)(t + 1) * MEMN + m0 + r) * HSZ + jp],
                               s_pub[r * 256 + jp], s_pub[r * 256 + jp + 1]);
                    }
                if (lane < 16) st_wt(&g_Mn[(size_t)(t + 1) * MEMN + m0 + lane], s_Mn[lane]);
                wait_vm0();
                if (lane == 0) st_flag(&g_fC[((size_t)t * NWG_C + nc) * FSP], t + 1);
            } else if (wv == 14 && t + 1 < TSTEPS - 1) {
                wait_flags16(g_fB + (size_t)t * NWG_B * FSP, NWG_B, t + 1, lane);
            } else if (wv == 15 && t + 1 < TSTEPS - 1) {
                wait_flags16(g_fA + (size_t)(t + 1) * NWG_A * FSP, NWG_A, t + 2, lane);
            }
            __syncthreads();
        }
    }
}

extern "C" void kernel_launch(void* const* d_in, const int* in_sizes, int n_in,
                              void* d_out, int out_size, void* d_ws, size_t ws_size,
                              hipStream_t stream) {
    const float* X   = (const float*)d_in[0];
    const float* Wih = (const float*)d_in[1];
    const float* Whh = (const float*)d_in[2];
    const float* bih = (const float*)d_in[3];
    const float* bhh = (const float*)d_in[4];
    float* out = (float*)d_out;
    (void)in_sizes; (void)n_in; (void)out_size; (void)d_ws; (void)ws_size;

    hipLaunchKernelGGL(reset_ctrl_kernel, dim3(1024), dim3(256), 0, stream);
    hipLaunchKernelGGL(pre_kernel, dim3(2048), dim3(256), 0, stream, X, Wih, bih, bhh);
    hipLaunchKernelGGL(mann_persist, dim3(NWG), dim3(NTHR), 0, stream, Whh, out);
}